// Round 1
// baseline (688.325 us; speedup 1.0000x reference)
//
#include <hip/hip_runtime.h>

#define HALF 128
#define NMAT 16384   // 128*128
#define NTOK 131072  // 32*4096

// ---------------------------------------------------------------------------
// K1a: in-place Gauss-Jordan inverse of M^T (M = I - A/2, A = skew(tril(X)))
// One block per matrix. Ms = M^T in LDS; on exit Ms = (M^T)^{-1}; dumped to ws.
// No pivoting needed: symmetric part of M^T is I (positive definite).
// ---------------------------------------------------------------------------
__global__ __launch_bounds__(256) void gj_inverse(const float* __restrict__ prim,
                                                  float* __restrict__ MinvT) {
    __shared__ float Ms[HALF * HALF];   // 64 KB
    const int b   = blockIdx.x;
    const float* __restrict__ X = prim + b * NMAT;
    const int tid = threadIdx.x;

    // Load Ms[i][j] = M[j][i]. A[r][c] = X[r][c] (r>c), -X[c][r] (r<c), 0 diag.
    for (int idx = tid; idx < NMAT; idx += 256) {
        int i = idx >> 7, j = idx & 127;
        float v;
        if (i == j)      v = 1.0f;
        else if (j > i)  v = -0.5f * X[j * HALF + i];   // M[j][i], j>i
        else             v =  0.5f * X[i * HALF + j];   // M[j][i], j<i
        Ms[idx] = v;
    }
    __syncthreads();

    const int grp = tid >> 5;            // 8 groups of 32 lanes; group owns rows it*8+grp
    const int j4  = (tid & 31) << 2;     // 4-float column chunk -> conflict-free LDS

    for (int k = 0; k < 128; ++k) {
        float d  = 1.0f / Ms[k * HALF + k];
        float nd = -d;
        // Fused column update + rank-1 update (row k untouched until phase C)
        for (int it = 0; it < 16; ++it) {
            int i = it * 8 + grp;
            if (i != k) {
                float corig = Ms[i * HALF + k];       // broadcast within group
                float c = corig * nd;                 // new column-k value
                float4 rk = *(const float4*)&Ms[k * HALF + j4];
                bool q = ((j4 >> 2) == (k >> 2));     // mask col k out of the FMA
                rk.x = (q && ((k & 3) == 0)) ? 0.f : rk.x;
                rk.y = (q && ((k & 3) == 1)) ? 0.f : rk.y;
                rk.z = (q && ((k & 3) == 2)) ? 0.f : rk.z;
                rk.w = (q && ((k & 3) == 3)) ? 0.f : rk.w;
                float4 m = *(float4*)&Ms[i * HALF + j4];
                m.x += c * rk.x; m.y += c * rk.y; m.z += c * rk.z; m.w += c * rk.w;
                *(float4*)&Ms[i * HALF + j4] = m;
                if ((tid & 31) == 0) Ms[i * HALF + k] = c;  // one writer per row
            }
        }
        __syncthreads();
        if (tid < 128) {                  // phase C: scale original row k
            if (tid == k) Ms[k * HALF + k] = d;
            else          Ms[k * HALF + tid] *= d;
        }
        __syncthreads();
    }

    for (int idx = tid; idx < NMAT; idx += 256) MinvT[b * NMAT + idx] = Ms[idx];
}

// ---------------------------------------------------------------------------
// K1b: QT[b][k][j] = sum_t M[k][t] * MinvT[t][j]   (Q^T = M * (M^T)^{-1})
// M recomputed on the fly from X (lane-uniform -> scalar loads).
// Grid: 2 matrices x 16 k-blocks of 8 rows; 128 threads (lane = j).
// ---------------------------------------------------------------------------
__global__ __launch_bounds__(128) void qt_from_minvt(const float* __restrict__ prim,
                                                     const float* __restrict__ MinvT,
                                                     float* __restrict__ QT) {
    const int b     = blockIdx.x >> 4;
    const int kbase = (blockIdx.x & 15) << 3;
    const float* __restrict__ X  = prim  + b * NMAT;
    const float* __restrict__ MT = MinvT + b * NMAT;
    const int j = threadIdx.x;

    float acc[8] = {0.f,0.f,0.f,0.f,0.f,0.f,0.f,0.f};
    for (int t = 0; t < 128; ++t) {
        float mv = MT[t * HALF + j];          // coalesced, L2-hot
        #pragma unroll
        for (int kk = 0; kk < 8; ++kk) {
            int k = kbase + kk;
            float m;
            if (t == k)      m = 1.0f;
            else if (t < k)  m = -0.5f * X[k * HALF + t];
            else             m =  0.5f * X[t * HALF + k];
            acc[kk] += m * mv;
        }
    }
    #pragma unroll
    for (int kk = 0; kk < 8; ++kk)
        QT[b * NMAT + (kbase + kk) * HALF + j] = acc[kk];
}

// ---------------------------------------------------------------------------
// K2: path table P[v][j] = f(v) for all v in [0,4096).
// v = identity; for d: b = bit d of v if (v>>(d+1))>0 else skip; v = v @ Q_b^T
// out[j] = sum_k v[k] * QT[b][k][j].  8 rows/block, k-split over 2 thread halves.
// ---------------------------------------------------------------------------
__global__ __launch_bounds__(256) void path_table(const float* __restrict__ QT,
                                                  const float* __restrict__ ident,
                                                  float* __restrict__ P) {
    __shared__ float vs[8][HALF];
    __shared__ float part[8][HALF];
    const int tid = threadIdx.x;
    const int j   = tid & 127;
    const int kh  = tid >> 7;          // k-half: 0 or 1
    const int k0  = kh << 6;
    const int vbase = blockIdx.x << 3;

    if (tid < 128) {
        float idv = ident[j];
        #pragma unroll
        for (int r = 0; r < 8; ++r) vs[r][j] = idv;
    }
    __syncthreads();

    const float* __restrict__ Q0 = QT;
    const float* __restrict__ Q1 = QT + NMAT;

    for (int d = 0; d < 13; ++d) {
        if (((vbase + 7) >> (d + 1)) == 0) break;   // block-uniform early exit
        int bb[8]; bool need0 = false, need1 = false;
        #pragma unroll
        for (int r = 0; r < 8; ++r) {
            int u = vbase + r;
            bb[r] = ((u >> (d + 1)) > 0) ? ((u >> d) & 1) : 2;
            need0 |= (bb[r] == 0);
            need1 |= (bb[r] == 1);
        }
        float acc[8] = {0.f,0.f,0.f,0.f,0.f,0.f,0.f,0.f};
        for (int k = k0; k < k0 + 64; k += 4) {
            float q00=0.f,q01=0.f,q02=0.f,q03=0.f,q10=0.f,q11=0.f,q12=0.f,q13=0.f;
            if (need0) {
                q00 = Q0[(k+0)*HALF + j]; q01 = Q0[(k+1)*HALF + j];
                q02 = Q0[(k+2)*HALF + j]; q03 = Q0[(k+3)*HALF + j];
            }
            if (need1) {
                q10 = Q1[(k+0)*HALF + j]; q11 = Q1[(k+1)*HALF + j];
                q12 = Q1[(k+2)*HALF + j]; q13 = Q1[(k+3)*HALF + j];
            }
            #pragma unroll
            for (int r = 0; r < 8; ++r) {
                if (bb[r] != 2) {
                    float4 vv = *(const float4*)&vs[r][k];   // broadcast read
                    if (bb[r] == 0) acc[r] += vv.x*q00 + vv.y*q01 + vv.z*q02 + vv.w*q03;
                    else            acc[r] += vv.x*q10 + vv.y*q11 + vv.z*q12 + vv.w*q13;
                }
            }
        }
        __syncthreads();                  // all vs reads complete
        if (kh == 1) {
            #pragma unroll
            for (int r = 0; r < 8; ++r) part[r][j] = acc[r];
        }
        __syncthreads();
        if (kh == 0) {
            #pragma unroll
            for (int r = 0; r < 8; ++r)
                if (bb[r] != 2) vs[r][j] = acc[r] + part[r][j];
        }
        __syncthreads();                  // writes visible before next step's reads
    }

    if (tid < 128) {
        #pragma unroll
        for (int r = 0; r < 8; ++r) P[(vbase + r) * HALF + j] = vs[r][j];
    }
}

// ---------------------------------------------------------------------------
// K3: emit output [B,S,256]: content (types/embeds/db->P[tv]) ++ pos (P[np]).
// unique/searchsorted bypassed: db token_values are always present positions.
// ---------------------------------------------------------------------------
__global__ __launch_bounds__(256) void emit_out(const int* __restrict__ tt,
                                                const int* __restrict__ tv,
                                                const int* __restrict__ np,
                                                const float* __restrict__ P,
                                                const float* __restrict__ emb,
                                                float* __restrict__ out) {
    const int base = blockIdx.x * 16;
    const int j = threadIdx.x;
    for (int s = 0; s < 16; ++s) {
        int i = base + s;
        int t = tt[i], v = tv[i], p = np[i];   // uniform -> scalar loads
        float val;
        if (j < 128) {
            if (t == 0)      val = emb[j];
            else if (t == 1) val = emb[(v + 1) * HALF + j];
            else if (t == 2) val = emb[(v + 5) * HALF + j];
            else if (t == 4) {
                int vc = v < 0 ? 0 : (v > 4095 ? 4095 : v);
                val = P[vc * HALF + j];
            } else           val = (v == -1) ? emb[10 * HALF + j] : 0.0f;
        } else {
            val = P[p * HALF + (j - 128)];
        }
        out[i * 256 + j] = val;
    }
}

extern "C" void kernel_launch(void* const* d_in, const int* in_sizes, int n_in,
                              void* d_out, int out_size, void* d_ws, size_t ws_size,
                              hipStream_t stream) {
    const int*   token_types = (const int*)  d_in[0];
    const int*   token_vals  = (const int*)  d_in[1];
    const int*   node_pos    = (const int*)  d_in[2];
    const float* prim        = (const float*)d_in[3];
    const float* ident       = (const float*)d_in[4];
    const float* emb         = (const float*)d_in[5];
    float* out = (float*)d_out;

    // workspace layout: QT[2][128][128] | MinvT[2][128][128] | P[4096][128]
    float* QT    = (float*)d_ws;
    float* MinvT = (float*)((char*)d_ws + 131072);
    float* P     = (float*)((char*)d_ws + 262144);

    gj_inverse  <<<2,    256, 0, stream>>>(prim, MinvT);
    qt_from_minvt<<<32,  128, 0, stream>>>(prim, MinvT, QT);
    path_table  <<<512,  256, 0, stream>>>(QT, ident, P);
    emit_out    <<<NTOK / 16, 256, 0, stream>>>(token_types, token_vals, node_pos,
                                                P, emb, out);
}